// Round 7
// baseline (170.835 us; speedup 1.0000x reference)
//
#include <hip/hip_runtime.h>
#include <hip/hip_bf16.h>

// Problem constants
#define BN_NODES 4096      // B*N = 8*512
#define KNN 16
#define C_POOL 256
#define G_DIM 128
#define IN_DIM 384         // C_POOL + G_DIM
#define L_DIM 512
#define OUT_STRIDE 1920    // 384 + 3*512

#define X1_OFF 384
#define X2_OFF 896
#define X3_OFF 1408

typedef __attribute__((ext_vector_type(8))) __bf16 bf16x8;
typedef __attribute__((ext_vector_type(4))) float floatx4;
typedef __attribute__((ext_vector_type(8))) unsigned short ushortx8;

static __device__ __forceinline__ ushort f2bf(float v) {
  return __builtin_bit_cast(ushort, __float2bfloat16(v));
}
static __device__ __forceinline__ float bf2f(ushort u) {
  return __builtin_bit_cast(float, ((unsigned)u) << 16);
}
static __device__ __forceinline__ void gld_lds(const ushort* g, ushort* l) {
  __builtin_amdgcn_global_load_lds(
      (const __attribute__((address_space(1))) void*)g,
      (__attribute__((address_space(3))) void*)l, 16, 0, 0);
}

// ---------------------------------------------------------------------------
// Kernel 1 (prep): blocks [0,256): node_feat, 16 nodes/block (halves gW2
//                  staging redundancy vs 8/block; 256 blocks = 1/CU on all
//                  256 CUs);
//                  blocks [256,352): W0 bf16 conversion (4 ushort4/thread,
//                  literal K=384 -> magic-mul division).
// MLP2 reads gW2 from LDS: coalesced global stage, row stride 129 floats ->
// lane bank (c+k)%32, 2-way = free. h1 reads are wave-broadcast (same addr).
// ---------------------------------------------------------------------------
__global__ __launch_bounds__(256) void prep_kernel(
    const float* __restrict__ rois, const float* __restrict__ pooled,
    const float* __restrict__ gW1, const float* __restrict__ gb1,
    const float* __restrict__ gW2, const float* __restrict__ gb2,
    const float* __restrict__ W0, float* __restrict__ out,
    ushort* __restrict__ Xb0, ushort* __restrict__ Wb0) {
  const int t = threadIdx.x;
  if (blockIdx.x >= 256) {
    // W0 conversion: 96 blocks x 256 threads x 4 ushort4-groups
    //   = 98304 groups x 4 elems = 1024*384 exactly.
    const int base = (blockIdx.x - 256) * 1024;
#pragma unroll
    for (int p = 0; p < 4; ++p) {
      int g = base + p * 256 + t;
      int elem = g * 4;
      int j = elem / IN_DIM;  // literal divisor -> magic-mul
      int k = elem - j * IN_DIM;
      const float* srcp =
          (j < 512) ? W0 + (size_t)j * (2 * IN_DIM) + k
                    : W0 + (size_t)(j - 512) * (2 * IN_DIM) + IN_DIM + k;
      ushort4 pk;
      pk.x = f2bf(srcp[0]);
      pk.y = f2bf(srcp[1]);
      pk.z = f2bf(srcp[2]);
      pk.w = f2bf(srcp[3]);
      *(ushort4*)(Wb0 + (size_t)j * IN_DIM + k) = pk;
    }
    return;
  }
  __shared__ float sW2[128 * 129];               // 66048 B, stride-129 rows
  __shared__ float rs[112];                      // 16 nodes x 7
  __shared__ __align__(16) float h1[16][G_DIM];  // 8 KB
  const int nb = blockIdx.x * 16;
  const int c = t & 127;
  const int nh = t >> 7;  // 0/1 -> 8 nodes each
  // stage gW2 coalesced: 16384 floats = 256 threads x 16 float4
  {
    const float4* g4 = (const float4*)gW2;
#pragma unroll
    for (int p = 0; p < 16; ++p) {
      int f = p * 256 + t;
      float4 v = g4[f];
      float* dst = &sW2[(f >> 5) * 129 + (f & 31) * 4];
      dst[0] = v.x;
      dst[1] = v.y;
      dst[2] = v.z;
      dst[3] = v.w;
    }
  }
  if (t < 112) rs[t] = rois[(size_t)nb * 7 + t];
  __syncthreads();
  {
    float w1[7];
#pragma unroll
    for (int i = 0; i < 7; i++) w1[i] = gW1[c * 7 + i];
    float b1 = gb1[c];
#pragma unroll
    for (int n = nh * 8; n < nh * 8 + 8; n++) {
      float a = b1;
#pragma unroll
      for (int i = 0; i < 7; i++) a += rs[n * 7 + i] * w1[i];
      h1[n][c] = fmaxf(a, 0.f);
    }
  }
  __syncthreads();
  float acc[8];
  {
    float b2 = gb2[c];
#pragma unroll
    for (int n = 0; n < 8; n++) acc[n] = b2;
    const float* wrow = &sW2[c * 129];
#pragma unroll 4
    for (int k4 = 0; k4 < G_DIM / 4; k4++) {
      float4 wv = *(const float4*)&wrow[k4 * 4];  // 2-way banks, free
#pragma unroll
      for (int n = 0; n < 8; n++) {
        float4 hv = ((const float4*)h1[nh * 8 + n])[k4];  // broadcast
        acc[n] += wv.x * hv.x + wv.y * hv.y + wv.z * hv.z + wv.w * hv.w;
      }
    }
  }
#pragma unroll
  for (int n = 0; n < 8; n++) {
    int node = nb + nh * 8 + n;
    float g = fmaxf(acc[n], 0.f);
    const float* prow = pooled + (size_t)node * C_POOL;
    float p0 = prow[c], p1 = prow[G_DIM + c];
    float* orow = out + (size_t)node * OUT_STRIDE;
    orow[c] = p0;
    orow[G_DIM + c] = p1;
    orow[C_POOL + c] = g;
    ushort* xrow = Xb0 + (size_t)node * IN_DIM;
    xrow[c] = f2bf(p0);
    xrow[G_DIM + c] = f2bf(p1);
    xrow[C_POOL + c] = f2bf(g);
  }
}

// ---------------------------------------------------------------------------
// Kernel 2: bf16 MFMA GEMM, 2-PHASE double-buffered (R4 structure, passed 3x).
// PQb[4096 x 1024] = Xb[4096 x K] @ Wb[1024 x K]^T.
// Tile 128x64, BK=64, 512 threads = 8 waves (4x2), wave = 32x32 (2x2 tiles).
// grid (32,16) = 512 blocks = 2 blocks/CU (LDS 48KB), 16 waves/CU.
// R7: epilogue repacks C through LDS (aliases sA after final barrier;
// 128x72-ushort padded tile, <=2-way banks) -> 2 fully-coalesced ushort8
// stores/thread instead of 16 scalar 2-B stores at 2KB stride (4 half-used
// 64B lines per wave-store, ~2x write amplification on 8MB x 3).
// ---------------------------------------------------------------------------
template <int K>
__global__ __launch_bounds__(512) void mfma_gemm_kernel(
    const ushort* __restrict__ Xb, const ushort* __restrict__ Wb,
    ushort* __restrict__ PQb) {
  __shared__ __align__(16) ushort sA[2][128 * 64];  // 2 x 16 KB
  __shared__ __align__(16) ushort sB[2][64 * 64];   // 2 x 8 KB
  const int tid = threadIdx.x;
  const int lane = tid & 63;
  const int w = tid >> 6;          // wave 0..7
  const int wm = w >> 1;           // 0..3 (32-row band)
  const int wn = w & 1;            // 0..1 (32-col band)
  const int fr = lane & 15;
  const int kc = lane >> 4;
  const int bm = blockIdx.x, bn = blockIdx.y;
  constexpr int NT = K / 64;

  // wave-uniform staging tile coords (A: 2 tiles/wave, B: 1 tile/wave)
  const int ta0 = w, ta1 = w + 8;
  const int rt0 = ta0 >> 1, ks0 = ta0 & 1;
  const int rt1 = ta1 >> 1, ks1 = ta1 & 1;
  const int ctB = w >> 1, ksB = w & 1;
  const ushort* gA0 =
      Xb + (size_t)(bm * 128 + rt0 * 16 + fr) * K + ks0 * 32 + kc * 8;
  const ushort* gA1 =
      Xb + (size_t)(bm * 128 + rt1 * 16 + fr) * K + ks1 * 32 + kc * 8;
  const ushort* gB =
      Wb + (size_t)(bn * 64 + ctB * 16 + fr) * K + ksB * 32 + kc * 8;

  floatx4 acc[2][2];
#pragma unroll
  for (int i = 0; i < 2; i++)
#pragma unroll
    for (int j = 0; j < 2; j++) acc[i][j] = (floatx4){0.f, 0.f, 0.f, 0.f};

  // prologue: stage k-step 0 into buf 0
  gld_lds(gA0, &sA[0][ta0 * 512 + lane * 8]);
  gld_lds(gA1, &sA[0][ta1 * 512 + lane * 8]);
  gld_lds(gB, &sB[0][w * 512 + lane * 8]);
  __syncthreads();  // vmcnt(0) drain before first read

#pragma unroll
  for (int t = 0; t < NT; ++t) {
    const int cur = t & 1;
    // stage next k-step into the other buffer (overlaps with MFMA below)
    if (t + 1 < NT) {
      const int k0n = (t + 1) * 64;
      gld_lds(gA0 + k0n, &sA[cur ^ 1][ta0 * 512 + lane * 8]);
      gld_lds(gA1 + k0n, &sA[cur ^ 1][ta1 * 512 + lane * 8]);
      gld_lds(gB + k0n, &sB[cur ^ 1][w * 512 + lane * 8]);
    }
#pragma unroll
    for (int ks = 0; ks < 2; ks++) {
      bf16x8 af[2], bfr[2];
#pragma unroll
      for (int i = 0; i < 2; i++)
        af[i] =
            *(const bf16x8*)&sA[cur][((wm * 2 + i) * 2 + ks) * 512 + lane * 8];
#pragma unroll
      for (int j = 0; j < 2; j++)
        bfr[j] =
            *(const bf16x8*)&sB[cur][((wn * 2 + j) * 2 + ks) * 512 + lane * 8];
#pragma unroll
      for (int i = 0; i < 2; i++)
#pragma unroll
        for (int j = 0; j < 2; j++)
          acc[i][j] = __builtin_amdgcn_mfma_f32_16x16x32_bf16(af[i], bfr[j],
                                                              acc[i][j], 0, 0,
                                                              0);
    }
    __syncthreads();  // drains staged vmcnt + all lgkm reads of buf[cur]
  }

  // ---- coalesced epilogue via LDS repack.
  // C/D layout: col = fr, row = kc*4 + reg (m89-verified).
  // sC aliases sA (safe: final K-loop barrier above orders all MFMA reads
  // before these writes). 128x72 ushort (18KB); pad 8 -> row bank rotate 4;
  // 16-lane row-groups write 8 dwords, kc0/kc2 alias 2-way = free (m136).
  ushort* sC = &sA[0][0];
  {
    const int rowL = wm * 32 + kc * 4;
    const int colL = wn * 32 + fr;
#pragma unroll
    for (int i = 0; i < 2; i++)
#pragma unroll
      for (int j = 0; j < 2; j++)
#pragma unroll
        for (int r = 0; r < 4; r++)
          sC[(rowL + i * 16 + r) * 72 + colL + j * 16] = f2bf(acc[i][j][r]);
  }
  __syncthreads();
  {
    const int row = tid >> 3;      // 0..63
    const int c8 = (tid & 7) * 8;  // 0..56
#pragma unroll
    for (int h = 0; h < 2; h++) {
      int rr = row + h * 64;
      ushortx8 v = *(const ushortx8*)&sC[rr * 72 + c8];  // 16B-aligned
      *(ushortx8*)&PQb[(size_t)(bm * 128 + rr) * 1024 + bn * 64 + c8] = v;
    }
  }
}

// ---------------------------------------------------------------------------
// Kernel 3: edge gather + max + relu. One WAVE per node; lane = 8 channels
// (16 B). XCD-batch swizzle: node = (bid&7)*512 + (bid>>3)*8 + wave_id.
// wconv tail converts the NEXT layer's weight (W1 in edge-1, W2 in edge-2;
// K=512 -> shift/mask). Read by the next GEMM only (boundary-ordered).
// ---------------------------------------------------------------------------
__global__ __launch_bounds__(512) void edge_kernel(
    const ushort* __restrict__ PQb, const int* __restrict__ src,
    const float* __restrict__ bias, float* __restrict__ out, int out_off,
    ushort* __restrict__ Xb, int write_x, const float* __restrict__ wsrc,
    ushort* __restrict__ wdst) {
  const int bid = blockIdx.x;
  const int n = (bid & 7) * 512 + (bid >> 3) * 8 + (threadIdx.x >> 6);
  const int l = threadIdx.x & 63;

  int nbr[KNN];
  {
    const int4* sp = (const int4*)(src + (size_t)n * KNN);
#pragma unroll
    for (int k4 = 0; k4 < 4; k4++) {
      int4 v = sp[k4];  // same addr across wave -> broadcast
      nbr[k4 * 4 + 0] = v.x;
      nbr[k4 * 4 + 1] = v.y;
      nbr[k4 * 4 + 2] = v.z;
      nbr[k4 * 4 + 3] = v.w;
    }
  }

  const ushort* own = PQb + (size_t)n * 1024 + l * 8;
  ushortx8 pu = *(const ushortx8*)own;
  ushortx8 qu = *(const ushortx8*)(own + 512);

  float m[8];
#pragma unroll
  for (int c = 0; c < 8; c++) m[c] = -1e30f;
#pragma unroll
  for (int k = 0; k < KNN; k++) {
    ushortx8 u = *(const ushortx8*)(PQb + (size_t)nbr[k] * 1024 + l * 8);
#pragma unroll
    for (int c = 0; c < 8; c++) m[c] = fmaxf(m[c], bf2f(u[c]));
  }

  const float4 bb0 = *(const float4*)&bias[l * 8];
  const float4 bb1 = *(const float4*)&bias[l * 8 + 4];
  float res[8];
#pragma unroll
  for (int c = 0; c < 8; c++) {
    float bbv = (c < 4) ? ((const float*)&bb0)[c] : ((const float*)&bb1)[c - 4];
    res[c] = fmaxf(m[c] - bf2f(pu[c]) + bf2f(qu[c]) + bbv, 0.f);
  }

  float* orow = out + (size_t)n * OUT_STRIDE + out_off + l * 8;
  *(float4*)orow = (float4){res[0], res[1], res[2], res[3]};
  *(float4*)(orow + 4) = (float4){res[4], res[5], res[6], res[7]};
  if (write_x) {
    ushortx8 pk;
#pragma unroll
    for (int c = 0; c < 8; c++) pk[c] = f2bf(res[c]);
    *(ushortx8*)(Xb + (size_t)n * L_DIM + l * 8) = pk;
  }

  // ---- wconv tail (independent; K=512): 1024*512 elems = 131072 ushort4
  //      groups over the first 256 blocks' 512 threads.
  if (wsrc != nullptr) {
    int g = bid * 512 + threadIdx.x;
    if (g < 131072) {
      int elem = g * 4;
      int j = elem >> 9;  // /512
      int k = elem & 511;
      const float* srcp = (j < 512)
                              ? wsrc + ((size_t)j << 10) + k
                              : wsrc + ((size_t)(j - 512) << 10) + 512 + k;
      ushort4 pk;
      pk.x = f2bf(srcp[0]);
      pk.y = f2bf(srcp[1]);
      pk.z = f2bf(srcp[2]);
      pk.w = f2bf(srcp[3]);
      *(ushort4*)(wdst + ((size_t)j << 9) + k) = pk;
    }
  }
}

extern "C" void kernel_launch(void* const* d_in, const int* in_sizes, int n_in,
                              void* d_out, int out_size, void* d_ws,
                              size_t ws_size, hipStream_t stream) {
  const float* rois = (const float*)d_in[0];
  const float* pooled = (const float*)d_in[1];
  const int* edge_index = (const int*)d_in[2];
  const float* gW1 = (const float*)d_in[3];
  const float* gb1 = (const float*)d_in[4];
  const float* gW2 = (const float*)d_in[5];
  const float* gb2 = (const float*)d_in[6];
  const float* fcW[3] = {(const float*)d_in[7], (const float*)d_in[9],
                         (const float*)d_in[11]};
  const float* fcb[3] = {(const float*)d_in[8], (const float*)d_in[10],
                         (const float*)d_in[12]};
  float* out = (float*)d_out;
  const int* src = edge_index;  // dst[e] == e/16 by construction

  // workspace layout (bytes) — HARD CAP 15 MB total, do not grow:
  //   PQb : 4096*1024 bf16 = 8 MB  @ 0
  //   Xb  : 4096*512  bf16 = 4 MB  @ 8 MB  (stride IN_DIM for x0, L_DIM after)
  //   Wb0 : 1024*384  bf16         @ 12 MB
  //   Wb1 : 1024*512  bf16         @ 13 MB
  //   Wb2 : 1024*512  bf16         @ 14 MB  (last store ends exactly at 15 MB)
  char* ws = (char*)d_ws;
  ushort* PQb = (ushort*)ws;
  ushort* Xb = (ushort*)(ws + (size_t)8 * 1024 * 1024);
  ushort* Wb[3] = {(ushort*)(ws + (size_t)12 * 1024 * 1024),
                   (ushort*)(ws + (size_t)13 * 1024 * 1024),
                   (ushort*)(ws + (size_t)14 * 1024 * 1024)};

  prep_kernel<<<352, 256, 0, stream>>>(rois, pooled, gW1, gb1, gW2, gb2,
                                       fcW[0], out, Xb, Wb[0]);

  mfma_gemm_kernel<IN_DIM><<<dim3(32, 16), 512, 0, stream>>>(Xb, Wb[0], PQb);
  edge_kernel<<<512, 512, 0, stream>>>(PQb, src, fcb[0], out, X1_OFF, Xb, 1,
                                       fcW[1], Wb[1]);
  mfma_gemm_kernel<L_DIM><<<dim3(32, 16), 512, 0, stream>>>(Xb, Wb[1], PQb);
  edge_kernel<<<512, 512, 0, stream>>>(PQb, src, fcb[1], out, X2_OFF, Xb, 1,
                                       fcW[2], Wb[2]);
  mfma_gemm_kernel<L_DIM><<<dim3(32, 16), 512, 0, stream>>>(Xb, Wb[2], PQb);
  edge_kernel<<<512, 512, 0, stream>>>(PQb, src, fcb[2], out, X3_OFF, Xb, 0,
                                       nullptr, nullptr);
}

// Round 8
// 166.188 us; speedup vs baseline: 1.0280x; 1.0280x over previous
//
#include <hip/hip_runtime.h>
#include <hip/hip_bf16.h>

// Problem constants
#define BN_NODES 4096      // B*N = 8*512
#define KNN 16
#define C_POOL 256
#define G_DIM 128
#define IN_DIM 384         // C_POOL + G_DIM
#define L_DIM 512
#define OUT_STRIDE 1920    // 384 + 3*512

#define X1_OFF 384
#define X2_OFF 896
#define X3_OFF 1408

typedef __attribute__((ext_vector_type(8))) __bf16 bf16x8;
typedef __attribute__((ext_vector_type(4))) float floatx4;
typedef __attribute__((ext_vector_type(8))) unsigned short ushortx8;

static __device__ __forceinline__ ushort f2bf(float v) {
  return __builtin_bit_cast(ushort, __float2bfloat16(v));
}
static __device__ __forceinline__ float bf2f(ushort u) {
  return __builtin_bit_cast(float, ((unsigned)u) << 16);
}
static __device__ __forceinline__ void gld_lds(const ushort* g, ushort* l) {
  __builtin_amdgcn_global_load_lds(
      (const __attribute__((address_space(1))) void*)g,
      (__attribute__((address_space(3))) void*)l, 16, 0, 0);
}

// ---------------------------------------------------------------------------
// Kernel 1 (prep): blocks [0,512): node_feat (8 nodes/block);
//                  blocks [512,608): W0 bf16 conversion (4 ushort4/thread,
//                  literal K=384 -> magic-mul division).
// MLP2 reads gW2 from LDS (coalesced global stage, row stride 129 ->
// bank (c+k)%32, 2-way = free). [R6 configuration — session-best 166.7us;
// R7's 16-node/block + GEMM LDS-repack variant regressed to 170.8us.]
// ---------------------------------------------------------------------------
__global__ __launch_bounds__(256) void prep_kernel(
    const float* __restrict__ rois, const float* __restrict__ pooled,
    const float* __restrict__ gW1, const float* __restrict__ gb1,
    const float* __restrict__ gW2, const float* __restrict__ gb2,
    const float* __restrict__ W0, float* __restrict__ out,
    ushort* __restrict__ Xb0, ushort* __restrict__ Wb0) {
  const int t = threadIdx.x;
  if (blockIdx.x >= 512) {
    // W0 conversion: 96 blocks x 256 threads x 4 ushort4-groups
    //   = 98304 groups x 4 elems = 1024*384 exactly.
    const int base = (blockIdx.x - 512) * 1024;
#pragma unroll
    for (int p = 0; p < 4; ++p) {
      int g = base + p * 256 + t;
      int elem = g * 4;
      int j = elem / IN_DIM;         // literal divisor -> magic-mul
      int k = elem - j * IN_DIM;
      const float* srcp = (j < 512)
                              ? W0 + (size_t)j * (2 * IN_DIM) + k
                              : W0 + (size_t)(j - 512) * (2 * IN_DIM) + IN_DIM + k;
      ushort4 pk;
      pk.x = f2bf(srcp[0]);
      pk.y = f2bf(srcp[1]);
      pk.z = f2bf(srcp[2]);
      pk.w = f2bf(srcp[3]);
      *(ushort4*)(Wb0 + (size_t)j * IN_DIM + k) = pk;
    }
    return;
  }
  __shared__ float sW2[128 * 129];              // 66048 B, stride-129 rows
  __shared__ float rs[64];
  __shared__ __align__(16) float h1[8][G_DIM];  // 4 KB
  const int nb = blockIdx.x * 8;
  const int c = t & 127;
  const int nh = t >> 7;
  // stage gW2 coalesced: 16384 floats = 256 threads x 16 float4
  {
    const float4* g4 = (const float4*)gW2;
#pragma unroll
    for (int p = 0; p < 16; ++p) {
      int f = p * 256 + t;
      float4 v = g4[f];
      float* dst = &sW2[(f >> 5) * 129 + (f & 31) * 4];
      dst[0] = v.x;
      dst[1] = v.y;
      dst[2] = v.z;
      dst[3] = v.w;
    }
  }
  if (t < 56) rs[t] = rois[(size_t)nb * 7 + t];
  __syncthreads();
  {
    float w1[7];
#pragma unroll
    for (int i = 0; i < 7; i++) w1[i] = gW1[c * 7 + i];
    float b1 = gb1[c];
#pragma unroll
    for (int n = nh * 4; n < nh * 4 + 4; n++) {
      float a = b1;
#pragma unroll
      for (int i = 0; i < 7; i++) a += rs[n * 7 + i] * w1[i];
      h1[n][c] = fmaxf(a, 0.f);
    }
  }
  __syncthreads();
  float acc[4];
  {
    float b2 = gb2[c];
#pragma unroll
    for (int n = 0; n < 4; n++) acc[n] = b2;
    const float* wrow = &sW2[c * 129];
#pragma unroll 4
    for (int k4 = 0; k4 < G_DIM / 4; k4++) {
      float4 hv[4];
#pragma unroll
      for (int n = 0; n < 4; n++) hv[n] = ((const float4*)h1[nh * 4 + n])[k4];
#pragma unroll
      for (int q = 0; q < 4; q++) {
        float wv = wrow[k4 * 4 + q];  // bank (c+k)%32: 2-way, free
#pragma unroll
        for (int n = 0; n < 4; n++)
          acc[n] += wv * ((const float*)&hv[n])[q];
      }
    }
  }
#pragma unroll
  for (int n = 0; n < 4; n++) {
    int node = nb + nh * 4 + n;
    float g = fmaxf(acc[n], 0.f);
    const float* prow = pooled + (size_t)node * C_POOL;
    float p0 = prow[c], p1 = prow[G_DIM + c];
    float* orow = out + (size_t)node * OUT_STRIDE;
    orow[c] = p0;
    orow[G_DIM + c] = p1;
    orow[C_POOL + c] = g;
    ushort* xrow = Xb0 + (size_t)node * IN_DIM;
    xrow[c] = f2bf(p0);
    xrow[G_DIM + c] = f2bf(p1);
    xrow[C_POOL + c] = f2bf(g);
  }
}

// ---------------------------------------------------------------------------
// Kernel 2: bf16 MFMA GEMM, 2-PHASE double-buffered (R4/R6 structure).
// PQb[4096 x 1024] = Xb[4096 x K] @ Wb[1024 x K]^T.
// Tile 128x64, BK=64, 512 threads = 8 waves (4x2), wave = 32x32 (2x2 tiles).
// grid (32,16) = 512 blocks = 2 blocks/CU (LDS 48KB), 16 waves/CU.
// Per K-step: STAGE(next buf) issued BEFORE compute(cur buf); one barrier
// per step. Direct scalar C-store (R7's LDS-repack epilogue regressed +4us:
// extra barrier + LDS pass cost more than the write-amplification saved).
// ---------------------------------------------------------------------------
template <int K>
__global__ __launch_bounds__(512) void mfma_gemm_kernel(
    const ushort* __restrict__ Xb, const ushort* __restrict__ Wb,
    ushort* __restrict__ PQb) {
  __shared__ __align__(16) ushort sA[2][128 * 64];  // 2 x 16 KB
  __shared__ __align__(16) ushort sB[2][64 * 64];   // 2 x 8 KB
  const int tid = threadIdx.x;
  const int lane = tid & 63;
  const int w = tid >> 6;          // wave 0..7
  const int wm = w >> 1;           // 0..3 (32-row band)
  const int wn = w & 1;            // 0..1 (32-col band)
  const int fr = lane & 15;
  const int kc = lane >> 4;
  const int bm = blockIdx.x, bn = blockIdx.y;
  constexpr int NT = K / 64;

  // wave-uniform staging tile coords (A: 2 tiles/wave, B: 1 tile/wave)
  const int ta0 = w, ta1 = w + 8;
  const int rt0 = ta0 >> 1, ks0 = ta0 & 1;
  const int rt1 = ta1 >> 1, ks1 = ta1 & 1;
  const int ctB = w >> 1, ksB = w & 1;
  const ushort* gA0 =
      Xb + (size_t)(bm * 128 + rt0 * 16 + fr) * K + ks0 * 32 + kc * 8;
  const ushort* gA1 =
      Xb + (size_t)(bm * 128 + rt1 * 16 + fr) * K + ks1 * 32 + kc * 8;
  const ushort* gB =
      Wb + (size_t)(bn * 64 + ctB * 16 + fr) * K + ksB * 32 + kc * 8;

  floatx4 acc[2][2];
#pragma unroll
  for (int i = 0; i < 2; i++)
#pragma unroll
    for (int j = 0; j < 2; j++) acc[i][j] = (floatx4){0.f, 0.f, 0.f, 0.f};

  // prologue: stage k-step 0 into buf 0
  gld_lds(gA0, &sA[0][ta0 * 512 + lane * 8]);
  gld_lds(gA1, &sA[0][ta1 * 512 + lane * 8]);
  gld_lds(gB, &sB[0][w * 512 + lane * 8]);
  __syncthreads();  // vmcnt(0) drain before first read

#pragma unroll
  for (int t = 0; t < NT; ++t) {
    const int cur = t & 1;
    // stage next k-step into the other buffer (overlaps with MFMA below)
    if (t + 1 < NT) {
      const int k0n = (t + 1) * 64;
      gld_lds(gA0 + k0n, &sA[cur ^ 1][ta0 * 512 + lane * 8]);
      gld_lds(gA1 + k0n, &sA[cur ^ 1][ta1 * 512 + lane * 8]);
      gld_lds(gB + k0n, &sB[cur ^ 1][w * 512 + lane * 8]);
    }
#pragma unroll
    for (int ks = 0; ks < 2; ks++) {
      bf16x8 af[2], bfr[2];
#pragma unroll
      for (int i = 0; i < 2; i++)
        af[i] =
            *(const bf16x8*)&sA[cur][((wm * 2 + i) * 2 + ks) * 512 + lane * 8];
#pragma unroll
      for (int j = 0; j < 2; j++)
        bfr[j] =
            *(const bf16x8*)&sB[cur][((wn * 2 + j) * 2 + ks) * 512 + lane * 8];
#pragma unroll
      for (int i = 0; i < 2; i++)
#pragma unroll
        for (int j = 0; j < 2; j++)
          acc[i][j] = __builtin_amdgcn_mfma_f32_16x16x32_bf16(af[i], bfr[j],
                                                              acc[i][j], 0, 0,
                                                              0);
    }
    __syncthreads();  // drains staged vmcnt + all lgkm reads of buf[cur]
  }

  // C/D layout: col = fr, row = kc*4 + reg (m89-verified)
  const int rowB = bm * 128 + wm * 32 + kc * 4;
  const int colB = bn * 64 + wn * 32 + fr;
#pragma unroll
  for (int i = 0; i < 2; i++)
#pragma unroll
    for (int j = 0; j < 2; j++)
#pragma unroll
      for (int r = 0; r < 4; r++)
        PQb[(size_t)(rowB + i * 16 + r) * 1024 + colB + j * 16] =
            f2bf(acc[i][j][r]);
}

// ---------------------------------------------------------------------------
// Kernel 3: edge gather + max + relu. One WAVE per node; lane = 8 channels
// (16 B). XCD-batch swizzle: node = (bid&7)*512 + (bid>>3)*8 + wave_id.
// wconv tail converts the NEXT layer's weight (W1 in edge-1, W2 in edge-2;
// K=512 -> shift/mask). Read by the next GEMM only (boundary-ordered).
// ---------------------------------------------------------------------------
__global__ __launch_bounds__(512) void edge_kernel(
    const ushort* __restrict__ PQb, const int* __restrict__ src,
    const float* __restrict__ bias, float* __restrict__ out, int out_off,
    ushort* __restrict__ Xb, int write_x, const float* __restrict__ wsrc,
    ushort* __restrict__ wdst) {
  const int bid = blockIdx.x;
  const int n = (bid & 7) * 512 + (bid >> 3) * 8 + (threadIdx.x >> 6);
  const int l = threadIdx.x & 63;

  int nbr[KNN];
  {
    const int4* sp = (const int4*)(src + (size_t)n * KNN);
#pragma unroll
    for (int k4 = 0; k4 < 4; k4++) {
      int4 v = sp[k4];  // same addr across wave -> broadcast
      nbr[k4 * 4 + 0] = v.x;
      nbr[k4 * 4 + 1] = v.y;
      nbr[k4 * 4 + 2] = v.z;
      nbr[k4 * 4 + 3] = v.w;
    }
  }

  const ushort* own = PQb + (size_t)n * 1024 + l * 8;
  ushortx8 pu = *(const ushortx8*)own;
  ushortx8 qu = *(const ushortx8*)(own + 512);

  float m[8];
#pragma unroll
  for (int c = 0; c < 8; c++) m[c] = -1e30f;
#pragma unroll
  for (int k = 0; k < KNN; k++) {
    ushortx8 u = *(const ushortx8*)(PQb + (size_t)nbr[k] * 1024 + l * 8);
#pragma unroll
    for (int c = 0; c < 8; c++) m[c] = fmaxf(m[c], bf2f(u[c]));
  }

  const float4 bb0 = *(const float4*)&bias[l * 8];
  const float4 bb1 = *(const float4*)&bias[l * 8 + 4];
  float res[8];
#pragma unroll
  for (int c = 0; c < 8; c++) {
    float bbv = (c < 4) ? ((const float*)&bb0)[c] : ((const float*)&bb1)[c - 4];
    res[c] = fmaxf(m[c] - bf2f(pu[c]) + bf2f(qu[c]) + bbv, 0.f);
  }

  float* orow = out + (size_t)n * OUT_STRIDE + out_off + l * 8;
  *(float4*)orow = (float4){res[0], res[1], res[2], res[3]};
  *(float4*)(orow + 4) = (float4){res[4], res[5], res[6], res[7]};
  if (write_x) {
    ushortx8 pk;
#pragma unroll
    for (int c = 0; c < 8; c++) pk[c] = f2bf(res[c]);
    *(ushortx8*)(Xb + (size_t)n * L_DIM + l * 8) = pk;
  }

  // ---- wconv tail (independent; K=512): 1024*512 elems = 131072 ushort4
  //      groups over the first 256 blocks' 512 threads.
  if (wsrc != nullptr) {
    int g = bid * 512 + threadIdx.x;
    if (g < 131072) {
      int elem = g * 4;
      int j = elem >> 9;        // /512
      int k = elem & 511;
      const float* srcp = (j < 512) ? wsrc + ((size_t)j << 10) + k
                                    : wsrc + ((size_t)(j - 512) << 10) + 512 + k;
      ushort4 pk;
      pk.x = f2bf(srcp[0]);
      pk.y = f2bf(srcp[1]);
      pk.z = f2bf(srcp[2]);
      pk.w = f2bf(srcp[3]);
      *(ushort4*)(wdst + ((size_t)j << 9) + k) = pk;
    }
  }
}

extern "C" void kernel_launch(void* const* d_in, const int* in_sizes, int n_in,
                              void* d_out, int out_size, void* d_ws,
                              size_t ws_size, hipStream_t stream) {
  const float* rois = (const float*)d_in[0];
  const float* pooled = (const float*)d_in[1];
  const int* edge_index = (const int*)d_in[2];
  const float* gW1 = (const float*)d_in[3];
  const float* gb1 = (const float*)d_in[4];
  const float* gW2 = (const float*)d_in[5];
  const float* gb2 = (const float*)d_in[6];
  const float* fcW[3] = {(const float*)d_in[7], (const float*)d_in[9],
                         (const float*)d_in[11]};
  const float* fcb[3] = {(const float*)d_in[8], (const float*)d_in[10],
                         (const float*)d_in[12]};
  float* out = (float*)d_out;
  const int* src = edge_index;  // dst[e] == e/16 by construction

  // workspace layout (bytes) — HARD CAP 15 MB total, do not grow:
  //   PQb : 4096*1024 bf16 = 8 MB  @ 0
  //   Xb  : 4096*512  bf16 = 4 MB  @ 8 MB  (stride IN_DIM for x0, L_DIM after)
  //   Wb0 : 1024*384  bf16         @ 12 MB
  //   Wb1 : 1024*512  bf16         @ 13 MB
  //   Wb2 : 1024*512  bf16         @ 14 MB  (last store ends exactly at 15 MB)
  char* ws = (char*)d_ws;
  ushort* PQb = (ushort*)ws;
  ushort* Xb = (ushort*)(ws + (size_t)8 * 1024 * 1024);
  ushort* Wb[3] = {(ushort*)(ws + (size_t)12 * 1024 * 1024),
                   (ushort*)(ws + (size_t)13 * 1024 * 1024),
                   (ushort*)(ws + (size_t)14 * 1024 * 1024)};

  prep_kernel<<<608, 256, 0, stream>>>(rois, pooled, gW1, gb1, gW2, gb2,
                                       fcW[0], out, Xb, Wb[0]);

  mfma_gemm_kernel<IN_DIM><<<dim3(32, 16), 512, 0, stream>>>(Xb, Wb[0], PQb);
  edge_kernel<<<512, 512, 0, stream>>>(PQb, src, fcb[0], out, X1_OFF, Xb, 1,
                                       fcW[1], Wb[1]);
  mfma_gemm_kernel<L_DIM><<<dim3(32, 16), 512, 0, stream>>>(Xb, Wb[1], PQb);
  edge_kernel<<<512, 512, 0, stream>>>(PQb, src, fcb[1], out, X2_OFF, Xb, 1,
                                       fcW[2], Wb[2]);
  mfma_gemm_kernel<L_DIM><<<dim3(32, 16), 512, 0, stream>>>(Xb, Wb[2], PQb);
  edge_kernel<<<512, 512, 0, stream>>>(PQb, src, fcb[2], out, X3_OFF, Xb, 0,
                                       nullptr, nullptr);
}